// Round 8
// baseline (207.134 us; speedup 1.0000x reference)
//
#include <hip/hip_runtime.h>
#include <math.h>

// Problem constants
#define B_   32
#define P_   8
#define K_   17
#define H_   192
#define W_   192
#define HW_  (H_*W_)              // 36864
#define PB4   156672              // K*H*W/4 float4 per batch row
#define NBLKS 2048                // 8 blocks/CU persistent
#define PER_B_BLKS 64             // blocks per batch row
#define CHUNK 16384               // 64 blocks * 256 threads (float4 stride)
#define FULL_IT 9                 // 9*16384 = 147456 of 156672
#define REM4  9216                // remainder float4 per b
#define BCE4  294912              // B*H*W/4

#define KPU  (K_*P_)              // 136 stamp units per batch row
#define TSQ_UNITS   (B_*K_)       // 544
#define RADIUS 18                 // exp(-18) ~ 1.5e-8: negligible tail

// ws layout (floats)
#define WS_BLK   0                // 2048*8: (S2,Zu,Zv,A,bce) per block
#define WS_STAMP 16384            // 4352: cross partial per (b,k,p)
#define WS_TSQ   20736            // 544: sum(t^2) per (b,k)

typedef __attribute__((ext_vector_type(4))) float f4v;

__device__ inline f4v ntload4(const float* p) {
    return __builtin_nontemporal_load((const f4v*)p);
}
__device__ inline float ntload1(const float* p) {
    return __builtin_nontemporal_load(p);
}

__device__ inline float wave_red_sum(float v) {
    for (int o = 32; o; o >>= 1) v += __shfl_xor(v, o, 64);
    return v;
}

__device__ inline void kl_elem(float sv, float tv,
        float& S2, float& Zu, float& Zv, float& A) {
    S2 += sv*sv;
    float u = tv*0.5f, v = sv*0.5f;
    float eu = __expf(u);
    Zu += eu;
    A  += eu*(u - v);
    Zv += __expf(v);
}

// =====================================================================
// Persistent kernel, 2048 blocks x 256 thr. r8 change vs r7:
//   phase-1 K-stream FULLY unrolled (9 iters -> up to 18 NT float4
//   loads hoisted per wave) to raise per-wave MLP past the 6-deep
//   batches of r7 (r7: NT loads confirmed the dirty-L2/L3 service-path
//   theory, 76 -> 51.5 us; remaining gap is load-latency exposure).
//   Spill tripwire: WRITE_SIZE must stay < 1 MB (r3 lesson).
// MSE = S2 - 2*cross + tsq; KL max-free (verified absmax 0 since r5).
// =====================================================================
__global__ void __launch_bounds__(256) main_kernel(
        const float* __restrict__ s_pose, const float* __restrict__ t_pose,
        const float* __restrict__ kps,    const int* __restrict__ vis,
        const float* __restrict__ s_seg,  const float* __restrict__ mask,
        float* __restrict__ ws) {
    __shared__ float sred[4][5];
    __shared__ float gx_s[40], gy_s[40];

    const int blk = blockIdx.x;
    const int tid = threadIdx.x;
    const float inv18 = 1.0f / 18.0f;

    // ---------------- phase 1: pose stream (b-pinned) ----------------
    const int b  = blk >> 6;                     // 64 blocks per b
    const int lg = ((blk & 63) << 8) | tid;      // 0..16383 within b
    const float* s4 = s_pose + ((size_t)b*PB4 + lg)*4;
    const float* t4 = t_pose + ((size_t)b*PB4 + lg)*4;

    float S2 = 0.f, Zu = 0.f, Zv = 0.f, A = 0.f;

    // full unroll: compiler hoists the independent NT loads (VGPR
    // headroom: r7 ran at 28 VGPRs; 5 waves/SIMD at ~100 is still fine)
    f4v sv_r[FULL_IT], tv_r[FULL_IT];
#pragma unroll
    for (int j = 0; j < FULL_IT; j++) {
        sv_r[j] = ntload4(s4 + (size_t)j*CHUNK*4);
        tv_r[j] = ntload4(t4 + (size_t)j*CHUNK*4);
    }
#pragma unroll
    for (int j = 0; j < FULL_IT; j++) {
        kl_elem(sv_r[j].x, tv_r[j].x, S2, Zu, Zv, A);
        kl_elem(sv_r[j].y, tv_r[j].y, S2, Zu, Zv, A);
        kl_elem(sv_r[j].z, tv_r[j].z, S2, Zu, Zv, A);
        kl_elem(sv_r[j].w, tv_r[j].w, S2, Zu, Zv, A);
    }
    if (lg < REM4) {
        f4v sv = ntload4(s4 + (size_t)FULL_IT*CHUNK*4);
        f4v tv = ntload4(t4 + (size_t)FULL_IT*CHUNK*4);
        kl_elem(sv.x, tv.x, S2, Zu, Zv, A);
        kl_elem(sv.y, tv.y, S2, Zu, Zv, A);
        kl_elem(sv.z, tv.z, S2, Zu, Zv, A);
        kl_elem(sv.w, tv.w, S2, Zu, Zv, A);
    }

    // ---------------- phase 2: BCE (one iter per thread) ----------------
    float bce = 0.f;
    {
        int gid = (blk << 8) | tid;
        if (gid < BCE4) {
            f4v xv = ntload4(s_seg + (size_t)gid*4);
            f4v mv = ntload4(mask  + (size_t)gid*4);
            bce += fmaxf(xv.x, 0.f) - xv.x*mv.x + log1pf(__expf(-fabsf(xv.x)));
            bce += fmaxf(xv.y, 0.f) - xv.y*mv.y + log1pf(__expf(-fabsf(xv.y)));
            bce += fmaxf(xv.z, 0.f) - xv.z*mv.z + log1pf(__expf(-fabsf(xv.z)));
            bce += fmaxf(xv.w, 0.f) - xv.w*mv.w + log1pf(__expf(-fabsf(xv.w)));
        }
    }

    // ---------------- single 5-value block reduction ----------------
    S2  = wave_red_sum(S2);
    Zu  = wave_red_sum(Zu);
    Zv  = wave_red_sum(Zv);
    A   = wave_red_sum(A);
    bce = wave_red_sum(bce);
    {
        int w = tid >> 6;
        if ((tid & 63) == 0) {
            sred[w][0] = S2; sred[w][1] = Zu; sred[w][2] = Zv;
            sred[w][3] = A;  sred[w][4] = bce;
        }
    }
    __syncthreads();
    if (tid == 0) {
        float* o = ws + WS_BLK + (size_t)blk * 8;
#pragma unroll
        for (int c = 0; c < 5; c++)
            o[c] = sred[0][c] + sred[1][c] + sred[2][c] + sred[3][c];
    }

    // -------- phase 3: cross-term stamps, b-local ----------
    for (int j = blk & 63; j < KPU; j += 64) {
        __syncthreads();   // protect gx_s/gy_s + sred reuse
        int u   = b*KPU + j;
        int kk  = j / P_;
        int pp  = j - kk*P_;
        float kx = kps[((b*P_ + pp)*K_ + kk)*2 + 0];
        float ky = kps[((b*P_ + pp)*K_ + kk)*2 + 1];
        int   vv = vis[(b*P_ + pp)*K_ + kk];
        float fx = floorf(kx * 191.f);   // row center
        float fy = floorf(ky * 191.f);   // col center
        bool ok = (vv > 0) && fx >= 0.f && fx < 192.f && fy >= 0.f && fy < 192.f;
        float acc = 0.f;
        if (ok) {
            int X0 = max(0, (int)fx - RADIUS), X1 = min(H_-1, (int)fx + RADIUS);
            int Y0 = max(0, (int)fy - RADIUS), Y1 = min(W_-1, (int)fy + RADIUS);
            int nr = X1 - X0 + 1, nc = Y1 - Y0 + 1;
            if (tid < nr) {
                float d = (float)(X0 + tid) - fx;
                gx_s[tid] = __expf(-d*d*inv18);
            } else if (tid >= 64 && tid - 64 < nc) {
                float d = (float)(Y0 + tid - 64) - fy;
                gy_s[tid - 64] = __expf(-d*d*inv18);
            }
            __syncthreads();
            const float* pb = s_pose + (size_t)(b*K_ + kk) * HW_;
            int lim = nr << 6;
            for (int e = tid; e < lim; e += 256) {
                int row = e >> 6, col = e & 63;
                if (col < nc)
                    acc += ntload1(pb + (X0 + row)*W_ + (Y0 + col))
                           * gx_s[row] * gy_s[col];
            }
        }
        acc = wave_red_sum(acc);
        if ((tid & 63) == 0) sred[tid >> 6][0] = acc;
        __syncthreads();
        if (tid == 0)
            ws[WS_STAMP + u] = sred[0][0] + sred[1][0] + sred[2][0] + sred[3][0];
    }

    // ---------------- phase 4: tsq closed form (blocks 0..543) ----------
    if (blk < TSQ_UNITS) {
        __syncthreads();
        int bb = blk / K_, kk = blk - bb*K_;
        int pq = tid >> 2, p = pq >> 3, q = pq & 7, ln = tid & 3;
        float kxp = kps[((bb*P_ + p)*K_ + kk)*2 + 0];
        float kyp = kps[((bb*P_ + p)*K_ + kk)*2 + 1];
        float kxq = kps[((bb*P_ + q)*K_ + kk)*2 + 0];
        float kyq = kps[((bb*P_ + q)*K_ + kk)*2 + 1];
        int vp = vis[(bb*P_ + p)*K_ + kk];
        int vq = vis[(bb*P_ + q)*K_ + kk];
        float axp = floorf(kxp * 191.f), ayp = floorf(kyp * 191.f);
        float axq = floorf(kxq * 191.f), ayq = floorf(kyq * 191.f);
        bool okp = (vp > 0) && axp >= 0.f && axp < 192.f && ayp >= 0.f && ayp < 192.f;
        bool okq = (vq > 0) && axq >= 0.f && axq < 192.f && ayq >= 0.f && ayq < 192.f;
        float sx = 0.f, sy = 0.f;
        int i0 = ln * 48;
        for (int i = i0; i < i0 + 48; i++) {
            float da = (float)i - axp, db = (float)i - axq;
            sx += __expf(-(da*da + db*db)*inv18);
            float ea = (float)i - ayp, eb = (float)i - ayq;
            sy += __expf(-(ea*ea + eb*eb)*inv18);
        }
        sx += __shfl_xor(sx, 1, 64); sy += __shfl_xor(sy, 1, 64);
        sx += __shfl_xor(sx, 2, 64); sy += __shfl_xor(sy, 2, 64);
        float val = (ln == 0 && okp && okq) ? sx * sy : 0.f;
        val = wave_red_sum(val);
        if ((tid & 63) == 0) sred[tid >> 6][0] = val;
        __syncthreads();
        if (tid == 0)
            ws[WS_TSQ + blk] = sred[0][0] + sred[1][0] + sred[2][0] + sred[3][0];
    }
}

// =====================================================================
// finalize: 1 block x 256 threads; 8 threads per batch row b.
//   mse_b = S2_b - 2*cross_b + tsq_b ;  KL_b = A/Zu + log(Zv) - log(Zu)
// =====================================================================
__global__ void __launch_bounds__(256) finalize_kernel(
        const float* __restrict__ ws, const int* __restrict__ vis,
        float* __restrict__ out) {
    __shared__ float rS2[B_][8], rZu[B_][8], rZv[B_][8], rA[B_][8];
    __shared__ float rCr[B_][8], rTq[B_][8];
    __shared__ int   rVs[B_][8];
    __shared__ float skl[B_], skp[B_];
    __shared__ float bw[4];
    int tid = threadIdx.x;
    int b = tid >> 3, s = tid & 7;

    float S2 = 0.f, Zu = 0.f, Zv = 0.f, A = 0.f, cr = 0.f, tq = 0.f;
    for (int j = s; j < PER_B_BLKS; j += 8) {
        const float* p = ws + WS_BLK + (size_t)(b*PER_B_BLKS + j) * 8;
        S2 += p[0]; Zu += p[1]; Zv += p[2]; A += p[3];
    }
    for (int j = s; j < KPU; j += 8) cr += ws[WS_STAMP + b*KPU + j];
    for (int j = s; j < K_;  j += 8) tq += ws[WS_TSQ + b*K_ + j];
    int vs = 0;
    for (int m = s; m < P_*K_; m += 8) vs += vis[b*(P_*K_) + m];
    rS2[b][s] = S2; rZu[b][s] = Zu; rZv[b][s] = Zv; rA[b][s] = A;
    rCr[b][s] = cr; rTq[b][s] = tq; rVs[b][s] = vs;

    float bce = 0.f;
    for (int i = tid; i < NBLKS; i += 256)
        bce += ws[WS_BLK + (size_t)i * 8 + 4];
    bce = wave_red_sum(bce);
    if ((tid & 63) == 0) bw[tid >> 6] = bce;
    __syncthreads();

    if (tid < B_) {
        float tS2=0.f, tZu=0.f, tZv=0.f, tA=0.f, tCr=0.f, tTq=0.f; int tVs=0;
#pragma unroll
        for (int q2 = 0; q2 < 8; q2++) {
            tS2 += rS2[tid][q2]; tZu += rZu[tid][q2]; tZv += rZv[tid][q2];
            tA  += rA[tid][q2];  tCr += rCr[tid][q2]; tTq += rTq[tid][q2];
            tVs += rVs[tid][q2];
        }
        float mse = tS2 - 2.f*tCr + tTq;
        skl[tid] = tA/tZu + (logf(tZv) - logf(tZu));
        skp[tid] = mse / ((float)tVs + 1e-6f);
    }
    __syncthreads();

    if (tid == 0) {
        float kl = 0.f, kpv = 0.f;
        for (int i = 0; i < B_; i++) { kl += skl[i]; kpv += skp[i]; }
        float bsum = bw[0] + bw[1] + bw[2] + bw[3];
        float pose_distill = 4.0f * kl / (float)B_;   // TEMP^2=4, batchmean
        float task_seg  = bsum / (float)(B_ * HW_);
        float task_pose = kpv / (float)B_;
        // seg_distill == 0 exactly (softmax over a size-1 channel axis)
        out[0] = 0.5f * pose_distill + 0.5f * (task_seg + task_pose);
    }
}

extern "C" void kernel_launch(void* const* d_in, const int* in_sizes, int n_in,
                              void* d_out, int out_size, void* d_ws, size_t ws_size,
                              hipStream_t stream) {
    const float* s_seg  = (const float*)d_in[0];
    const float* s_pose = (const float*)d_in[1];
    // d_in[2] (t_seg_logits) unused: seg_distill == 0 exactly
    const float* t_pose = (const float*)d_in[3];
    const float* mask   = (const float*)d_in[4];
    const float* kps    = (const float*)d_in[5];
    const int*   vis    = (const int*)d_in[6];
    float* out = (float*)d_out;
    float* ws  = (float*)d_ws;

    main_kernel<<<NBLKS, 256, 0, stream>>>(s_pose, t_pose, kps, vis,
                                           s_seg, mask, ws);
    finalize_kernel<<<1, 256, 0, stream>>>(ws, vis, out);
}